// Round 7
// baseline (246.586 us; speedup 1.0000x reference)
//
#include <hip/hip_runtime.h>

typedef __bf16 bf16;
typedef __bf16 bf16x8 __attribute__((ext_vector_type(8)));
typedef unsigned short u16x8 __attribute__((ext_vector_type(8)));
typedef float f32x4 __attribute__((ext_vector_type(4)));
typedef int i32x4 __attribute__((ext_vector_type(4)));

#define HH 128
#define WW 128
#define HP 130

// ---------------------------------------------------------------------------
// prep: one launch for zero_rings (blocks 0..257), transpose_all (258..3329),
// build_bfrag (3330..3500). All three write disjoint buffers.
// ---------------------------------------------------------------------------
__global__ __launch_bounds__(256) void prep(
    const float* __restrict__ fs, const float* __restrict__ ctx,
    const float* __restrict__ x, const float* __restrict__ fw,
    const float* __restrict__ pw, const float* __restrict__ mw,
    bf16* __restrict__ fs_t, bf16* __restrict__ ctx_t, float* __restrict__ xp,
    bf16* __restrict__ dstPsf, bf16* __restrict__ dstOffm) {
  __shared__ float tile[64][65];
  const int bid = blockIdx.x;
  const int tid = threadIdx.x;

  if (bid < 258) {
    // ---- zero rings (~1 MB) ----
    const int idx = bid * 256 + tid;  // < 66048 exactly
    const f32x4 z = {0.f, 0.f, 0.f, 0.f};
    int r, chunk;
    char* base;
    if (idx < 33024) {
      chunk = idx & 7;
      int cell = idx >> 3;
      r = cell % 516;
      int bb = cell / 516;
      int b = bb & 3;
      bf16* out = (bb >> 2) ? ctx_t : fs_t;
      int row, col;
      if (r < 130)      { row = 0;   col = r; }
      else if (r < 260) { row = 129; col = r - 130; }
      else { int s = r - 260; row = 1 + (s >> 1); col = (s & 1) ? 129 : 0; }
      base = (char*)(out + ((size_t)(b * HP + row) * HP + col) * 64);
    } else {
      int i2 = idx - 33024;
      chunk = i2 & 15;
      int cell = i2 >> 4;
      r = cell % 516;
      int b = cell / 516;
      int row, col;
      if (r < 130)      { row = 0;   col = r; }
      else if (r < 260) { row = 129; col = r - 130; }
      else { int s = r - 260; row = 1 + (s >> 1); col = (s & 1) ? 129 : 0; }
      base = (char*)(xp + ((size_t)(b * HP + row) * HP + col) * 64);
    }
    *reinterpret_cast<f32x4*>(base + chunk * 16) = z;
    return;
  }

  if (bid < 3330) {
    // ---- transpose_all ----
    const int t = bid - 258;            // 0..3071 = 2 x 128 x 12
    const int bx = t & 1, by = (t >> 1) & 127, bz = t >> 8;
    const int b = bz & 3, which = bz >> 2;
    const float* in = which == 0 ? fs : (which == 1 ? ctx : x);
    const int y = by, x0 = bx * 64;
#pragma unroll
    for (int pass = 0; pass < 16; ++pass) {
      int ci = pass * 4 + (tid >> 6), xx = tid & 63;
      tile[ci][xx] = in[((b * 64 + ci) * HH + y) * WW + x0 + xx];
    }
    __syncthreads();
    if (which == 2) {
#pragma unroll
      for (int pass = 0; pass < 16; ++pass) {
        int xx = pass * 4 + (tid >> 6), ci = tid & 63;
        xp[((size_t)(b * HP + y + 1) * HP + (x0 + xx + 1)) * 64 + ci] = tile[ci][xx];
      }
    } else {
      bf16* out = which ? ctx_t : fs_t;
#pragma unroll
      for (int pass = 0; pass < 16; ++pass) {
        int xx = pass * 4 + (tid >> 6), ci = tid & 63;
        out[((size_t)(b * HP + y + 1) * HP + (x0 + xx + 1)) * 64 + ci] = (bf16)tile[ci][xx];
      }
    }
    return;
  }

  // ---- build_bfrag ----
  const int bx = bid - 3330;            // 0..170
  if (bx < 162) {
    int idx = bx * 256 + tid;           // total 4*18*9*64 = 41472
    int lane = idx & 63;
    int nt = (idx >> 6) % 9;
    int kc = ((idx >> 6) / 9) % 18;
    int cc = (idx >> 6) / 162;
    int np = cc * 144 + nt * 16 + (lane & 15);  // permuted column
    int n = (np & 63) * 9 + (np >> 6);          // original filter channel
    int q = lane >> 4;
    bf16x8 v;
#pragma unroll
    for (int j = 0; j < 8; ++j) {
      int k = kc * 32 + q * 8 + j;
      int tap = k >> 6, ci = k & 63;
      v[j] = (bf16)fw[(n * 64 + ci) * 9 + tap];
    }
    *reinterpret_cast<bf16x8*>(dstPsf + (size_t)idx * 8) = v;
  } else {
    int idx = (bx - 162) * 256 + tid;   // total 18*2*64 = 2304
    int lane = idx & 63;
    int nt = (idx >> 6) & 1;
    int kc = (idx >> 6) >> 1;
    int n = nt * 16 + (lane & 15);
    int q = lane >> 4;
    bf16x8 v;
#pragma unroll
    for (int j = 0; j < 8; ++j) {
      int k = kc * 32 + q * 8 + j;
      int tap = k >> 6, ci = k & 63;
      float w = 0.f;
      if (n < 18) w = pw[(n * 64 + ci) * 9 + tap];
      else if (n < 27) w = mw[((n - 18) * 64 + ci) * 9 + tap];
      v[j] = (bf16)w;
    }
    *reinterpret_cast<bf16x8*>(dstOffm + (size_t)idx * 8) = v;
  }
}

// ---------------------------------------------------------------------------
// Mega kernel v7: 512-thread blocks, PSF waves split (sg=4 row-groups) x
// (ng=2 nt-groups). Round-6 analysis: per-tile LDS reads/tap = 32*ng + 18*sg;
// (8,1) = 176 (B read 8x redundantly), (4,2) = 136 (-23%). acc[4][5]<=80 regs,
// ~3 waves/SIMD unchanged; LDS pipe was the largest consumer (~35% busy).
// ---------------------------------------------------------------------------
__global__ __launch_bounds__(512, 3) void conv_mega(
    const bf16* __restrict__ ctx_t, const bf16* __restrict__ fs_t,
    const bf16* __restrict__ Bf, const bf16* __restrict__ Bf2,
    const float* __restrict__ fb, const float* __restrict__ pb,
    const float* __restrict__ mb, bf16* __restrict__ Pg,
    float* __restrict__ OM, int b0, int offmN) {
  __shared__ __align__(16) char smem[78336];  // apatch 41472 + 2x Bsm 18432
  ushort* apatch = (ushort*)smem;
  const int tid = threadIdx.x;
  const int lane = tid & 63, wv = tid >> 6;   // wv in [0,8)
  const int q = lane >> 4, col = lane & 15;
  const int bid = blockIdx.x;

  if ((int)bid < offmN) {
    // ---------------- offset/mask conv (unchanged from v6) ----------------
    const int b = bid >> 6, t = bid & 63;
    const int h0 = (t >> 3) * 16, w0 = (t & 7) * 16;
    const ushort* Atu = (const ushort*)fs_t;
#pragma unroll
    for (int it = 0; it < 6; ++it) {
      int flat = it * 512 + tid;
      if (flat < 2592) {
        int px = flat >> 3, c8 = flat & 7;
        int py = px / 18, pxx = px - py * 18;
        u16x8 v = *(const u16x8*)(Atu + ((size_t)((b * HP + h0 + py) * HP + (w0 + pxx))) * 64 + c8 * 8);
        *(u16x8*)(apatch + px * 64 + ((c8 ^ (px & 7)) * 8)) = v;
      }
    }
    __syncthreads();
    f32x4 acc[2][2];
#pragma unroll
    for (int s = 0; s < 2; ++s) {
      acc[s][0] = (f32x4){0.f, 0.f, 0.f, 0.f};
      acc[s][1] = (f32x4){0.f, 0.f, 0.f, 0.f};
    }
    const bf16* bl = Bf2 + lane * 8;
#pragma unroll
    for (int dh = 0; dh < 3; ++dh)
#pragma unroll
      for (int dw = 0; dw < 3; ++dw) {
        const int tap = dh * 3 + dw;
        bf16x8 a[2][2];
#pragma unroll
        for (int s = 0; s < 2; ++s) {
          int p = (s * 8 + wv + dh) * 18 + (col + dw);
#pragma unroll
          for (int hf = 0; hf < 2; ++hf) {
            int ch = (hf * 4 + q) ^ (p & 7);
            a[s][hf] = *(const bf16x8*)((const bf16*)apatch + p * 64 + ch * 8);
          }
        }
#pragma unroll
        for (int hf = 0; hf < 2; ++hf)
#pragma unroll
          for (int nt = 0; nt < 2; ++nt) {
            bf16x8 bb = *(const bf16x8*)(bl + (size_t)(((tap * 2 + hf) * 2 + nt) * 512));
#pragma unroll
            for (int s = 0; s < 2; ++s)
              acc[s][nt] = __builtin_amdgcn_mfma_f32_16x16x32_bf16(a[s][hf], bb, acc[s][nt], 0, 0, 0);
          }
      }
    float* OMb = OM + (size_t)b * 16384 * 32;
#pragma unroll
    for (int nt = 0; nt < 2; ++nt) {
      int n = nt * 16 + col;
#pragma unroll
      for (int s = 0; s < 2; ++s) {
        int h = h0 + s * 8 + wv;
#pragma unroll
        for (int j = 0; j < 4; ++j) {
          int w = w0 + q * 4 + j;
          float v = acc[s][nt][j];
          float r;
          if (n < 18) r = v + pb[n];
          else if (n < 27) { float z = v + mb[n - 18]; r = 1.f / (1.f + __expf(-z)); }
          else r = 0.f;
          OMb[(size_t)(h * WW + w) * 32 + n] = r;
        }
      }
    }
    return;
  }

  // ---------------- PSF GEMM (dbuf Bsm, (4,2) wave split) ----------------
  const int pid = bid - offmN;
  const int cc = pid & 3;
  const int rest = pid >> 2;
  const int brel = rest >> 6;
  const int b = b0 + brel;
  const int t = rest & 63;
  const int h0 = (t >> 3) * 16, w0 = (t & 7) * 16;
  const int sg = wv & 3, ng = wv >> 2;   // 4 row-groups x 2 nt-groups
  char* BsmBase = smem + 41472;
  const char* BfC = (const char*)Bf + (size_t)cc * 165888;  // 18 kc * 9216 B

  // issue tap-0 B stage FIRST (latency hides under apatch staging)
  {
    const char* gs = BfC;
#pragma unroll
    for (int it = 0; it < 3; ++it) {
      int flat = it * 512 + wv * 64;
      if (flat < 1152) {
        __builtin_amdgcn_global_load_lds(
            (const __attribute__((address_space(1))) void*)(gs + (size_t)(flat + lane) * 16),
            (__attribute__((address_space(3))) void*)(BsmBase + flat * 16), 16, 0, 0);
      }
    }
  }

  const ushort* Atu = (const ushort*)ctx_t;
#pragma unroll
  for (int it = 0; it < 6; ++it) {
    int flat = it * 512 + tid;
    if (flat < 2592) {
      int px = flat >> 3, c8 = flat & 7;
      int py = px / 18, pxx = px - py * 18;
      u16x8 v = *(const u16x8*)(Atu + ((size_t)((b * HP + h0 + py) * HP + (w0 + pxx))) * 64 + c8 * 8);
      *(u16x8*)(apatch + px * 64 + ((c8 ^ (px & 7)) * 8)) = v;
    }
  }
  __syncthreads();   // apatch + tap-0 Bsm ready (vmcnt drained)

  f32x4 acc[4][5];   // ng=0 uses [..][0..4] (nt 0..4); ng=1 uses [..][0..3] (nt 5..8)
#pragma unroll
  for (int s = 0; s < 4; ++s)
#pragma unroll
    for (int n = 0; n < 5; ++n) acc[s][n] = (f32x4){0.f, 0.f, 0.f, 0.f};

  for (int tap = 0; tap < 9; ++tap) {
    const int cur = tap & 1;
    // issue NEXT tap's stage before this tap's compute (latency overlap)
    if (tap < 8) {
      const char* gs = BfC + (tap + 1) * 18432;
      char* ld = BsmBase + (cur ^ 1) * 18432;
#pragma unroll
      for (int it = 0; it < 3; ++it) {
        int flat = it * 512 + wv * 64;     // wave-uniform chunk base
        if (flat < 1152) {
          __builtin_amdgcn_global_load_lds(
              (const __attribute__((address_space(1))) void*)(gs + (size_t)(flat + lane) * 16),
              (__attribute__((address_space(3))) void*)(ld + flat * 16), 16, 0, 0);
        }
      }
    }

    const int dh = tap >= 6 ? 2 : (tap >= 3 ? 1 : 0);
    const int dw = tap - dh * 3;
    bf16x8 a[4][2];
#pragma unroll
    for (int s = 0; s < 4; ++s) {
      int p = (sg * 4 + s + dh) * 18 + (col + dw);
#pragma unroll
      for (int hf = 0; hf < 2; ++hf) {
        int ch = (hf * 4 + q) ^ (p & 7);
        a[s][hf] = *(const bf16x8*)((const bf16*)apatch + p * 64 + ch * 8);
      }
    }
    const bf16* Bsm = (const bf16*)(BsmBase + cur * 18432);
#pragma unroll
    for (int hf = 0; hf < 2; ++hf) {
#pragma unroll
      for (int nt = 0; nt < 5; ++nt) {
        if (ng && nt == 4) continue;          // ng1 covers only 4 nt
        const int ntg = ng * 5 + nt;          // global nt 0..8
        bf16x8 bb = *(const bf16x8*)(Bsm + (size_t)(hf * 9 + ntg) * 512 + lane * 8);
#pragma unroll
        for (int s = 0; s < 4; ++s)
          acc[s][nt] = __builtin_amdgcn_mfma_f32_16x16x32_bf16(a[s][hf], bb, acc[s][nt], 0, 0, 0);
      }
    }
    __syncthreads();   // buf[cur] reads done; implicit vmcnt drain for tap+1
  }

  // epilogue: P[px][n'] (n' = t9*64 + c), bias via inverse permutation
  bf16* Pp = Pg + (size_t)brel * 16384 * 576;
#pragma unroll
  for (int nt = 0; nt < 5; ++nt) {
    if (ng && nt == 4) continue;
    const int ntg = ng * 5 + nt;
    int np = cc * 144 + ntg * 16 + col;
    float bias = fb[(np & 63) * 9 + (np >> 6)];
#pragma unroll
    for (int s = 0; s < 4; ++s) {
      int h = h0 + sg * 4 + s;
#pragma unroll
      for (int j = 0; j < 4; ++j) {
        int w = w0 + q * 4 + j;
        Pp[(size_t)(h * WW + w) * 576 + np] = (bf16)(acc[s][nt][j] + bias);
      }
    }
  }
}

// ---------------------------------------------------------------------------
// Sampler v3: two-phase (per-(pixel,tap) weights computed ONCE in LDS, not
// 64x per channel) at proven occupancy (256,4). Boundary taps skipped.
// ---------------------------------------------------------------------------
__global__ __launch_bounds__(256, 4) void sampler(
    const bf16* __restrict__ Pg, const float* __restrict__ xp,
    const float* __restrict__ OM, float* __restrict__ out, int b0) {
  __shared__ float smem[64][21];
  __shared__ __align__(16) float wts[144][4];
  __shared__ __align__(16) int   offs[144][4];
  const int tid = threadIdx.x;
  const int wv = tid >> 6, c = tid & 63;
  const int blk = blockIdx.x;
  const int brel = blk >> 10;
  const int b = b0 + brel;
  const int h = (blk >> 3) & 127;
  const int w0 = (blk & 7) * 16;

  const float* xpb = xp + (size_t)b * (HP * HP * 64) + c;
  const float* OMb = OM + (size_t)b * 16384 * 32;
  const bf16* Pbase = Pg + ((size_t)brel * 16384 + h * WW + w0) * 576;

  // ---- phase 1: per-(pixel,tap) weights, computed once (not per channel) ----
  if (tid < 144) {
    const int pl = tid / 9, tap = tid - pl * 9;   // tap = i3*3+j3
    const int i3 = tap / 3, j3 = tap - i3 * 3;
    const int dh = (i3 == 0) ? -1 : 0, ri = (i3 == 0) ? 2 : (i3 - 1);
    const int dw = (j3 == 0) ? -1 : 0, rj = (j3 == 0) ? 2 : (j3 - 1);
    const int hh = h + dh, ww2 = w0 + pl + dw;
    f32x4 g = {0.f, 0.f, 0.f, 0.f};
    i32x4 o = {0, 0, 0, 0};
    if (hh >= 0 && ww2 >= 0) {
      const int np = ri * 3 + rj;
      const float* omp = OMb + (size_t)(hh * WW + ww2) * 32;
      float ox = omp[np], oy = omp[9 + np], mv = omp[18 + np];
      float px = (float)(hh + ri) + ox;
      float py = (float)(ww2 + rj) + oy;
      float fx = floorf(px), fy = floorf(py);
      float ltx = fminf(fmaxf(fx, 0.f), 129.f);
      float lty = fminf(fmaxf(fy, 0.f), 129.f);
      float rbx = fminf(fmaxf(fx + 1.f, 0.f), 129.f);
      float rby = fminf(fmaxf(fy + 1.f, 0.f), 129.f);
      float pxc = fminf(fmaxf(px, 0.f), 129.f);
      float pyc = fminf(fmaxf(py, 0.f), 129.f);
      g[0] = (1.f + ltx - pxc) * (1.f + lty - pyc) * mv;  // lt
      g[1] = (1.f - rbx + pxc) * (1.f - rby + pyc) * mv;  // rb
      g[2] = (1.f + ltx - pxc) * (1.f - rby + pyc) * mv;  // lb
      g[3] = (1.f - rbx + pxc) * (1.f + lty - pyc) * mv;  // rt
      int ix0 = (int)ltx, iy0 = (int)lty, ix1 = (int)rbx, iy1 = (int)rby;
      o[0] = (ix0 * HP + iy0) * 64;
      o[1] = (ix1 * HP + iy1) * 64;
      o[2] = (ix0 * HP + iy1) * 64;
      o[3] = (ix1 * HP + iy0) * 64;
    }
    *reinterpret_cast<f32x4*>(&wts[tid][0]) = g;
    *reinterpret_cast<i32x4*>(&offs[tid][0]) = o;
  }
  __syncthreads();

  // ---- phase 2: channel-parallel gather + FMA ----
#pragma unroll
  for (int k = 0; k < 4; ++k) {
    const int pl = wv * 4 + k;
    const int w = w0 + pl;
    const bf16* Pp = Pbase + (size_t)pl * 576;
    float res = 0.f;
#pragma unroll
    for (int tap = 0; tap < 9; ++tap) {
      const int i3 = tap / 3, j3 = tap - i3 * 3;
      if ((i3 == 0 && h == 0) || (j3 == 0 && w == 0)) continue;  // wave-uniform skip
      const int idx = pl * 9 + tap;
      f32x4 g = *reinterpret_cast<const f32x4*>(&wts[idx][0]);   // uniform bcast
      i32x4 o = *reinterpret_cast<const i32x4*>(&offs[idx][0]);  // uniform bcast
      float x_lt = xpb[o[0]];
      float x_rb = xpb[o[1]];
      float x_lb = xpb[o[2]];
      float x_rt = xpb[o[3]];
      float sv = g[0] * x_lt + g[1] * x_rb + g[2] * x_lb + g[3] * x_rt;
      float pv = (float)Pp[tap * 64 + c];
      res += pv * sv;
    }
    smem[c][pl] = res;
  }
  __syncthreads();
  const int c2 = tid >> 2;
  const int wi = (tid & 3) * 4;
  f32x4 v;
#pragma unroll
  for (int i = 0; i < 4; ++i) v[i] = smem[c2][wi + i];
  *reinterpret_cast<f32x4*>(out + ((size_t)(b * 64 + c2) * HH + h) * WW + w0 + wi) = v;
}

// ---------------------------------------------------------------------------
extern "C" void kernel_launch(void* const* d_in, const int* in_sizes, int n_in,
                              void* d_out, int out_size, void* d_ws, size_t ws_size,
                              hipStream_t stream) {
  (void)in_sizes; (void)n_in; (void)out_size;
  const float* fs  = (const float*)d_in[0];
  const float* ctx = (const float*)d_in[1];
  const float* x   = (const float*)d_in[2];
  const float* pw  = (const float*)d_in[3];
  const float* pb  = (const float*)d_in[4];
  const float* fw  = (const float*)d_in[5];
  const float* fb  = (const float*)d_in[6];
  const float* mw  = (const float*)d_in[7];
  const float* mb  = (const float*)d_in[8];

  char* ws = (char*)d_ws;
  bf16*  ctx_t = (bf16*)(ws);                   //  8,652,800
  bf16*  fs_t  = (bf16*)(ws + 8652800);         //  8,652,800
  float* xp    = (float*)(ws + 17305600);       // 17,305,600
  bf16*  Bf    = (bf16*)(ws + 34611200);        //    663,552
  bf16*  Bf2   = (bf16*)(ws + 35274752);        //     36,864
  float* OM    = (float*)(ws + 35311616);       //  8,388,608
  bf16*  Pg    = (bf16*)(ws + 43700224);        // 18,874,368 per batch

  // one prep launch: ring-zero + transposes + B-frag builds
  prep<<<3501, 256, 0, stream>>>(fs, ctx, x, fw, pw, mw,
                                 fs_t, ctx_t, xp, Bf, Bf2);

  const size_t need4 = 43700224 + 4ull * 18874368;  // 119,197,696 B for 4-batch Pg
  if (ws_size >= need4) {
    // merged path (only if workspace is big enough for 4-batch Pg)
    conv_mega<<<1280, 512, 0, stream>>>(ctx_t, fs_t, Bf, Bf2, fb, pb, mb, Pg, OM, 0, 256);
    sampler<<<4096, 256, 0, stream>>>(Pg, xp, OM, (float*)d_out, 0);
  } else {
    // proven 2-batch split (Pg holds 2 batches)
    conv_mega<<<768, 512, 0, stream>>>(ctx_t, fs_t, Bf, Bf2, fb, pb, mb, Pg, OM, 0, 256);
    sampler<<<2048, 256, 0, stream>>>(Pg, xp, OM, (float*)d_out, 0);
    conv_mega<<<512, 512, 0, stream>>>(ctx_t, fs_t, Bf, Bf2, fb, pb, mb, Pg, OM, 2, 0);
    sampler<<<2048, 256, 0, stream>>>(Pg, xp, OM, (float*)d_out, 2);
  }
}

// Round 8
// 193.955 us; speedup vs baseline: 1.2714x; 1.2714x over previous
//
#include <hip/hip_runtime.h>

typedef __bf16 bf16;
typedef __bf16 bf16x8 __attribute__((ext_vector_type(8)));
typedef unsigned short u16x8 __attribute__((ext_vector_type(8)));
typedef float f32x4 __attribute__((ext_vector_type(4)));
typedef int i32x4 __attribute__((ext_vector_type(4)));

#define HH 128
#define WW 128
#define HP 130

// ---------------------------------------------------------------------------
// prep: one launch for zero_rings (blocks 0..257), transpose_all (258..3329),
// build_bfrag (3330..3500). All three write disjoint buffers.
// ---------------------------------------------------------------------------
__global__ __launch_bounds__(256) void prep(
    const float* __restrict__ fs, const float* __restrict__ ctx,
    const float* __restrict__ x, const float* __restrict__ fw,
    const float* __restrict__ pw, const float* __restrict__ mw,
    bf16* __restrict__ fs_t, bf16* __restrict__ ctx_t, float* __restrict__ xp,
    bf16* __restrict__ dstPsf, bf16* __restrict__ dstOffm) {
  __shared__ float tile[64][65];
  const int bid = blockIdx.x;
  const int tid = threadIdx.x;

  if (bid < 258) {
    // ---- zero rings (~1 MB) ----
    const int idx = bid * 256 + tid;  // < 66048 exactly
    const f32x4 z = {0.f, 0.f, 0.f, 0.f};
    int r, chunk;
    char* base;
    if (idx < 33024) {
      chunk = idx & 7;
      int cell = idx >> 3;
      r = cell % 516;
      int bb = cell / 516;
      int b = bb & 3;
      bf16* out = (bb >> 2) ? ctx_t : fs_t;
      int row, col;
      if (r < 130)      { row = 0;   col = r; }
      else if (r < 260) { row = 129; col = r - 130; }
      else { int s = r - 260; row = 1 + (s >> 1); col = (s & 1) ? 129 : 0; }
      base = (char*)(out + ((size_t)(b * HP + row) * HP + col) * 64);
    } else {
      int i2 = idx - 33024;
      chunk = i2 & 15;
      int cell = i2 >> 4;
      r = cell % 516;
      int b = cell / 516;
      int row, col;
      if (r < 130)      { row = 0;   col = r; }
      else if (r < 260) { row = 129; col = r - 130; }
      else { int s = r - 260; row = 1 + (s >> 1); col = (s & 1) ? 129 : 0; }
      base = (char*)(xp + ((size_t)(b * HP + row) * HP + col) * 64);
    }
    *reinterpret_cast<f32x4*>(base + chunk * 16) = z;
    return;
  }

  if (bid < 3330) {
    // ---- transpose_all ----
    const int t = bid - 258;            // 0..3071 = 2 x 128 x 12
    const int bx = t & 1, by = (t >> 1) & 127, bz = t >> 8;
    const int b = bz & 3, which = bz >> 2;
    const float* in = which == 0 ? fs : (which == 1 ? ctx : x);
    const int y = by, x0 = bx * 64;
#pragma unroll
    for (int pass = 0; pass < 16; ++pass) {
      int ci = pass * 4 + (tid >> 6), xx = tid & 63;
      tile[ci][xx] = in[((b * 64 + ci) * HH + y) * WW + x0 + xx];
    }
    __syncthreads();
    if (which == 2) {
#pragma unroll
      for (int pass = 0; pass < 16; ++pass) {
        int xx = pass * 4 + (tid >> 6), ci = tid & 63;
        xp[((size_t)(b * HP + y + 1) * HP + (x0 + xx + 1)) * 64 + ci] = tile[ci][xx];
      }
    } else {
      bf16* out = which ? ctx_t : fs_t;
#pragma unroll
      for (int pass = 0; pass < 16; ++pass) {
        int xx = pass * 4 + (tid >> 6), ci = tid & 63;
        out[((size_t)(b * HP + y + 1) * HP + (x0 + xx + 1)) * 64 + ci] = (bf16)tile[ci][xx];
      }
    }
    return;
  }

  // ---- build_bfrag ----
  const int bx = bid - 3330;            // 0..170
  if (bx < 162) {
    int idx = bx * 256 + tid;           // total 4*18*9*64 = 41472
    int lane = idx & 63;
    int nt = (idx >> 6) % 9;
    int kc = ((idx >> 6) / 9) % 18;
    int cc = (idx >> 6) / 162;
    int np = cc * 144 + nt * 16 + (lane & 15);  // permuted column
    int n = (np & 63) * 9 + (np >> 6);          // original filter channel
    int q = lane >> 4;
    bf16x8 v;
#pragma unroll
    for (int j = 0; j < 8; ++j) {
      int k = kc * 32 + q * 8 + j;
      int tap = k >> 6, ci = k & 63;
      v[j] = (bf16)fw[(n * 64 + ci) * 9 + tap];
    }
    *reinterpret_cast<bf16x8*>(dstPsf + (size_t)idx * 8) = v;
  } else {
    int idx = (bx - 162) * 256 + tid;   // total 18*2*64 = 2304
    int lane = idx & 63;
    int nt = (idx >> 6) & 1;
    int kc = (idx >> 6) >> 1;
    int n = nt * 16 + (lane & 15);
    int q = lane >> 4;
    bf16x8 v;
#pragma unroll
    for (int j = 0; j < 8; ++j) {
      int k = kc * 32 + q * 8 + j;
      int tap = k >> 6, ci = k & 63;
      float w = 0.f;
      if (n < 18) w = pw[(n * 64 + ci) * 9 + tap];
      else if (n < 27) w = mw[((n - 18) * 64 + ci) * 9 + tap];
      v[j] = (bf16)w;
    }
    *reinterpret_cast<bf16x8*>(dstOffm + (size_t)idx * 8) = v;
  }
}

// ---------------------------------------------------------------------------
// Mega kernel v8: REVERT to the proven v6 (8,1) wave split (round-7's (4,2)
// split spilled acc to scratch: WRITE +56MB, FETCH +19.5MB, dur 51->114us).
// Single addition: A-fragment reads for tap+1 are issued BEFORE the per-tap
// barrier — apatch is read-only after the prologue, so this is pure
// reordering; it overlaps the A ds_read latency with the barrier drain.
// ---------------------------------------------------------------------------
__global__ __launch_bounds__(512, 4) void conv_mega(
    const bf16* __restrict__ ctx_t, const bf16* __restrict__ fs_t,
    const bf16* __restrict__ Bf, const bf16* __restrict__ Bf2,
    const float* __restrict__ fb, const float* __restrict__ pb,
    const float* __restrict__ mb, bf16* __restrict__ Pg,
    float* __restrict__ OM, int b0, int offmN) {
  __shared__ __align__(16) char smem[78336];  // apatch 41472 + 2x Bsm 18432
  ushort* apatch = (ushort*)smem;
  const int tid = threadIdx.x;
  const int lane = tid & 63, wv = tid >> 6;   // wv in [0,8)
  const int q = lane >> 4, col = lane & 15;
  const int bid = blockIdx.x;

  if ((int)bid < offmN) {
    // ---------------- offset/mask conv (v6, unchanged) ----------------
    const int b = bid >> 6, t = bid & 63;
    const int h0 = (t >> 3) * 16, w0 = (t & 7) * 16;
    const ushort* Atu = (const ushort*)fs_t;
#pragma unroll
    for (int it = 0; it < 6; ++it) {
      int flat = it * 512 + tid;
      if (flat < 2592) {
        int px = flat >> 3, c8 = flat & 7;
        int py = px / 18, pxx = px - py * 18;
        u16x8 v = *(const u16x8*)(Atu + ((size_t)((b * HP + h0 + py) * HP + (w0 + pxx))) * 64 + c8 * 8);
        *(u16x8*)(apatch + px * 64 + ((c8 ^ (px & 7)) * 8)) = v;
      }
    }
    __syncthreads();
    f32x4 acc[2][2];
#pragma unroll
    for (int s = 0; s < 2; ++s) {
      acc[s][0] = (f32x4){0.f, 0.f, 0.f, 0.f};
      acc[s][1] = (f32x4){0.f, 0.f, 0.f, 0.f};
    }
    const bf16* bl = Bf2 + lane * 8;
#pragma unroll
    for (int dh = 0; dh < 3; ++dh)
#pragma unroll
      for (int dw = 0; dw < 3; ++dw) {
        const int tap = dh * 3 + dw;
        bf16x8 a[2][2];
#pragma unroll
        for (int s = 0; s < 2; ++s) {
          int p = (s * 8 + wv + dh) * 18 + (col + dw);
#pragma unroll
          for (int hf = 0; hf < 2; ++hf) {
            int ch = (hf * 4 + q) ^ (p & 7);
            a[s][hf] = *(const bf16x8*)((const bf16*)apatch + p * 64 + ch * 8);
          }
        }
#pragma unroll
        for (int hf = 0; hf < 2; ++hf)
#pragma unroll
          for (int nt = 0; nt < 2; ++nt) {
            bf16x8 bb = *(const bf16x8*)(bl + (size_t)(((tap * 2 + hf) * 2 + nt) * 512));
#pragma unroll
            for (int s = 0; s < 2; ++s)
              acc[s][nt] = __builtin_amdgcn_mfma_f32_16x16x32_bf16(a[s][hf], bb, acc[s][nt], 0, 0, 0);
          }
      }
    float* OMb = OM + (size_t)b * 16384 * 32;
#pragma unroll
    for (int nt = 0; nt < 2; ++nt) {
      int n = nt * 16 + col;
#pragma unroll
      for (int s = 0; s < 2; ++s) {
        int h = h0 + s * 8 + wv;
#pragma unroll
        for (int j = 0; j < 4; ++j) {
          int w = w0 + q * 4 + j;
          float v = acc[s][nt][j];
          float r;
          if (n < 18) r = v + pb[n];
          else if (n < 27) { float z = v + mb[n - 18]; r = 1.f / (1.f + __expf(-z)); }
          else r = 0.f;
          OMb[(size_t)(h * WW + w) * 32 + n] = r;
        }
      }
    }
    return;
  }

  // ---------------- PSF GEMM (v6 dbuf Bsm + A-prefetch) ----------------
  const int pid = bid - offmN;
  const int cc = pid & 3;
  const int rest = pid >> 2;
  const int brel = rest >> 6;
  const int b = b0 + brel;
  const int t = rest & 63;
  const int h0 = (t >> 3) * 16, w0 = (t & 7) * 16;
  char* BsmBase = smem + 41472;
  const char* BfC = (const char*)Bf + (size_t)cc * 165888;  // 18 kc * 9216 B

  // issue tap-0 B stage FIRST (latency hides under apatch staging)
  {
    const char* gs = BfC;
#pragma unroll
    for (int it = 0; it < 3; ++it) {
      int flat = it * 512 + wv * 64;
      if (flat < 1152) {
        __builtin_amdgcn_global_load_lds(
            (const __attribute__((address_space(1))) void*)(gs + (size_t)(flat + lane) * 16),
            (__attribute__((address_space(3))) void*)(BsmBase + flat * 16), 16, 0, 0);
      }
    }
  }

  const ushort* Atu = (const ushort*)ctx_t;
#pragma unroll
  for (int it = 0; it < 6; ++it) {
    int flat = it * 512 + tid;
    if (flat < 2592) {
      int px = flat >> 3, c8 = flat & 7;
      int py = px / 18, pxx = px - py * 18;
      u16x8 v = *(const u16x8*)(Atu + ((size_t)((b * HP + h0 + py) * HP + (w0 + pxx))) * 64 + c8 * 8);
      *(u16x8*)(apatch + px * 64 + ((c8 ^ (px & 7)) * 8)) = v;
    }
  }
  __syncthreads();   // apatch + tap-0 Bsm ready (vmcnt drained)

  f32x4 acc[2][9];
#pragma unroll
  for (int s = 0; s < 2; ++s)
#pragma unroll
    for (int n = 0; n < 9; ++n) acc[s][n] = (f32x4){0.f, 0.f, 0.f, 0.f};

  // pre-load A fragments for tap 0 (dh=0, dw=0)
  bf16x8 a_cur[2][2];
#pragma unroll
  for (int s = 0; s < 2; ++s) {
    int p = (s * 8 + wv) * 18 + col;
#pragma unroll
    for (int hf = 0; hf < 2; ++hf) {
      int ch = (hf * 4 + q) ^ (p & 7);
      a_cur[s][hf] = *(const bf16x8*)((const bf16*)apatch + p * 64 + ch * 8);
    }
  }

  for (int tap = 0; tap < 9; ++tap) {
    const int cur = tap & 1;
    // issue NEXT tap's B stage before this tap's compute (latency overlap)
    if (tap < 8) {
      const char* gs = BfC + (tap + 1) * 18432;
      char* ld = BsmBase + (cur ^ 1) * 18432;
#pragma unroll
      for (int it = 0; it < 3; ++it) {
        int flat = it * 512 + wv * 64;     // wave-uniform chunk base
        if (flat < 1152) {
          __builtin_amdgcn_global_load_lds(
              (const __attribute__((address_space(1))) void*)(gs + (size_t)(flat + lane) * 16),
              (__attribute__((address_space(3))) void*)(ld + flat * 16), 16, 0, 0);
        }
      }
    }

    const bf16* Bsm = (const bf16*)(BsmBase + cur * 18432);
#pragma unroll
    for (int hf = 0; hf < 2; ++hf) {
      const bf16* bp = Bsm + (size_t)(hf * 9) * 512 + lane * 8;
#pragma unroll
      for (int nt = 0; nt < 9; ++nt) {
        bf16x8 bb = *(const bf16x8*)(bp + nt * 512);
#pragma unroll
        for (int s = 0; s < 2; ++s)
          acc[s][nt] = __builtin_amdgcn_mfma_f32_16x16x32_bf16(a_cur[s][hf], bb, acc[s][nt], 0, 0, 0);
      }
    }

    // prefetch A for tap+1 from apatch (read-only after prologue) BEFORE the
    // barrier — overlaps A ds_read latency with the barrier's vmcnt drain.
    if (tap < 8) {
      const int tn = tap + 1;
      const int dh = tn >= 6 ? 2 : (tn >= 3 ? 1 : 0);
      const int dw = tn - dh * 3;
#pragma unroll
      for (int s = 0; s < 2; ++s) {
        int p = (s * 8 + wv + dh) * 18 + (col + dw);
#pragma unroll
        for (int hf = 0; hf < 2; ++hf) {
          int ch = (hf * 4 + q) ^ (p & 7);
          a_cur[s][hf] = *(const bf16x8*)((const bf16*)apatch + p * 64 + ch * 8);
        }
      }
    }
    // one barrier per tap: buf[cur] reads done; implicit vmcnt drain
    // completes the tap+1 stage (mostly already landed under the MFMAs)
    __syncthreads();
  }

  // epilogue: P[px][n'] (n' = t9*64 + c), bias via inverse permutation
  bf16* Pp = Pg + (size_t)brel * 16384 * 576;
#pragma unroll
  for (int nt = 0; nt < 9; ++nt) {
    int np = cc * 144 + nt * 16 + col;
    float bias = fb[(np & 63) * 9 + (np >> 6)];
#pragma unroll
    for (int s = 0; s < 2; ++s) {
      int h = h0 + s * 8 + wv;
#pragma unroll
      for (int j = 0; j < 4; ++j) {
        int w = w0 + q * 4 + j;
        Pp[(size_t)(h * WW + w) * 576 + np] = (bf16)(acc[s][nt][j] + bias);
      }
    }
  }
}

// ---------------------------------------------------------------------------
// Sampler v3: two-phase (per-(pixel,tap) weights computed ONCE in LDS, not
// 64x per channel) at proven occupancy (256,4). Boundary taps skipped.
// ---------------------------------------------------------------------------
__global__ __launch_bounds__(256, 4) void sampler(
    const bf16* __restrict__ Pg, const float* __restrict__ xp,
    const float* __restrict__ OM, float* __restrict__ out, int b0) {
  __shared__ float smem[64][21];
  __shared__ __align__(16) float wts[144][4];
  __shared__ __align__(16) int   offs[144][4];
  const int tid = threadIdx.x;
  const int wv = tid >> 6, c = tid & 63;
  const int blk = blockIdx.x;
  const int brel = blk >> 10;
  const int b = b0 + brel;
  const int h = (blk >> 3) & 127;
  const int w0 = (blk & 7) * 16;

  const float* xpb = xp + (size_t)b * (HP * HP * 64) + c;
  const float* OMb = OM + (size_t)b * 16384 * 32;
  const bf16* Pbase = Pg + ((size_t)brel * 16384 + h * WW + w0) * 576;

  // ---- phase 1: per-(pixel,tap) weights, computed once (not per channel) ----
  if (tid < 144) {
    const int pl = tid / 9, tap = tid - pl * 9;   // tap = i3*3+j3
    const int i3 = tap / 3, j3 = tap - i3 * 3;
    const int dh = (i3 == 0) ? -1 : 0, ri = (i3 == 0) ? 2 : (i3 - 1);
    const int dw = (j3 == 0) ? -1 : 0, rj = (j3 == 0) ? 2 : (j3 - 1);
    const int hh = h + dh, ww2 = w0 + pl + dw;
    f32x4 g = {0.f, 0.f, 0.f, 0.f};
    i32x4 o = {0, 0, 0, 0};
    if (hh >= 0 && ww2 >= 0) {
      const int np = ri * 3 + rj;
      const float* omp = OMb + (size_t)(hh * WW + ww2) * 32;
      float ox = omp[np], oy = omp[9 + np], mv = omp[18 + np];
      float px = (float)(hh + ri) + ox;
      float py = (float)(ww2 + rj) + oy;
      float fx = floorf(px), fy = floorf(py);
      float ltx = fminf(fmaxf(fx, 0.f), 129.f);
      float lty = fminf(fmaxf(fy, 0.f), 129.f);
      float rbx = fminf(fmaxf(fx + 1.f, 0.f), 129.f);
      float rby = fminf(fmaxf(fy + 1.f, 0.f), 129.f);
      float pxc = fminf(fmaxf(px, 0.f), 129.f);
      float pyc = fminf(fmaxf(py, 0.f), 129.f);
      g[0] = (1.f + ltx - pxc) * (1.f + lty - pyc) * mv;  // lt
      g[1] = (1.f - rbx + pxc) * (1.f - rby + pyc) * mv;  // rb
      g[2] = (1.f + ltx - pxc) * (1.f - rby + pyc) * mv;  // lb
      g[3] = (1.f - rbx + pxc) * (1.f + lty - pyc) * mv;  // rt
      int ix0 = (int)ltx, iy0 = (int)lty, ix1 = (int)rbx, iy1 = (int)rby;
      o[0] = (ix0 * HP + iy0) * 64;
      o[1] = (ix1 * HP + iy1) * 64;
      o[2] = (ix0 * HP + iy1) * 64;
      o[3] = (ix1 * HP + iy0) * 64;
    }
    *reinterpret_cast<f32x4*>(&wts[tid][0]) = g;
    *reinterpret_cast<i32x4*>(&offs[tid][0]) = o;
  }
  __syncthreads();

  // ---- phase 2: channel-parallel gather + FMA ----
#pragma unroll
  for (int k = 0; k < 4; ++k) {
    const int pl = wv * 4 + k;
    const int w = w0 + pl;
    const bf16* Pp = Pbase + (size_t)pl * 576;
    float res = 0.f;
#pragma unroll
    for (int tap = 0; tap < 9; ++tap) {
      const int i3 = tap / 3, j3 = tap - i3 * 3;
      if ((i3 == 0 && h == 0) || (j3 == 0 && w == 0)) continue;  // wave-uniform skip
      const int idx = pl * 9 + tap;
      f32x4 g = *reinterpret_cast<const f32x4*>(&wts[idx][0]);   // uniform bcast
      i32x4 o = *reinterpret_cast<const i32x4*>(&offs[idx][0]);  // uniform bcast
      float x_lt = xpb[o[0]];
      float x_rb = xpb[o[1]];
      float x_lb = xpb[o[2]];
      float x_rt = xpb[o[3]];
      float sv = g[0] * x_lt + g[1] * x_rb + g[2] * x_lb + g[3] * x_rt;
      float pv = (float)Pp[tap * 64 + c];
      res += pv * sv;
    }
    smem[c][pl] = res;
  }
  __syncthreads();
  const int c2 = tid >> 2;
  const int wi = (tid & 3) * 4;
  f32x4 v;
#pragma unroll
  for (int i = 0; i < 4; ++i) v[i] = smem[c2][wi + i];
  *reinterpret_cast<f32x4*>(out + ((size_t)(b * 64 + c2) * HH + h) * WW + w0 + wi) = v;
}

// ---------------------------------------------------------------------------
extern "C" void kernel_launch(void* const* d_in, const int* in_sizes, int n_in,
                              void* d_out, int out_size, void* d_ws, size_t ws_size,
                              hipStream_t stream) {
  (void)in_sizes; (void)n_in; (void)out_size;
  const float* fs  = (const float*)d_in[0];
  const float* ctx = (const float*)d_in[1];
  const float* x   = (const float*)d_in[2];
  const float* pw  = (const float*)d_in[3];
  const float* pb  = (const float*)d_in[4];
  const float* fw  = (const float*)d_in[5];
  const float* fb  = (const float*)d_in[6];
  const float* mw  = (const float*)d_in[7];
  const float* mb  = (const float*)d_in[8];

  char* ws = (char*)d_ws;
  bf16*  ctx_t = (bf16*)(ws);                   //  8,652,800
  bf16*  fs_t  = (bf16*)(ws + 8652800);         //  8,652,800
  float* xp    = (float*)(ws + 17305600);       // 17,305,600
  bf16*  Bf    = (bf16*)(ws + 34611200);        //    663,552
  bf16*  Bf2   = (bf16*)(ws + 35274752);        //     36,864
  float* OM    = (float*)(ws + 35311616);       //  8,388,608
  bf16*  Pg    = (bf16*)(ws + 43700224);        // 18,874,368 per batch

  // one prep launch: ring-zero + transposes + B-frag builds
  prep<<<3501, 256, 0, stream>>>(fs, ctx, x, fw, pw, mw,
                                 fs_t, ctx_t, xp, Bf, Bf2);

  const size_t need4 = 43700224 + 4ull * 18874368;  // 119,197,696 B for 4-batch Pg
  if (ws_size >= need4) {
    // merged path (harness ws = 256 MiB, so this is the live path)
    conv_mega<<<1280, 512, 0, stream>>>(ctx_t, fs_t, Bf, Bf2, fb, pb, mb, Pg, OM, 0, 256);
    sampler<<<4096, 256, 0, stream>>>(Pg, xp, OM, (float*)d_out, 0);
  } else {
    // fallback 2-batch split (Pg holds 2 batches)
    conv_mega<<<768, 512, 0, stream>>>(ctx_t, fs_t, Bf, Bf2, fb, pb, mb, Pg, OM, 0, 256);
    sampler<<<2048, 256, 0, stream>>>(Pg, xp, OM, (float*)d_out, 0);
    conv_mega<<<512, 512, 0, stream>>>(ctx_t, fs_t, Bf, Bf2, fb, pb, mb, Pg, OM, 2, 0);
    sampler<<<2048, 256, 0, stream>>>(Pg, xp, OM, (float*)d_out, 2);
  }
}

// Round 9
// 186.044 us; speedup vs baseline: 1.3254x; 1.0425x over previous
//
#include <hip/hip_runtime.h>

typedef __bf16 bf16;
typedef __bf16 bf16x8 __attribute__((ext_vector_type(8)));
typedef unsigned short u16x8 __attribute__((ext_vector_type(8)));
typedef float f32x4 __attribute__((ext_vector_type(4)));
typedef int i32x4 __attribute__((ext_vector_type(4)));

#define HH 128
#define WW 128
#define HP 130

// ---------------------------------------------------------------------------
// prep: one launch for zero_rings (blocks 0..257), transpose_all (258..3329),
// build_bfrag (3330..3500). All three write disjoint buffers.
// ---------------------------------------------------------------------------
__global__ __launch_bounds__(256) void prep(
    const float* __restrict__ fs, const float* __restrict__ ctx,
    const float* __restrict__ x, const float* __restrict__ fw,
    const float* __restrict__ pw, const float* __restrict__ mw,
    bf16* __restrict__ fs_t, bf16* __restrict__ ctx_t, float* __restrict__ xp,
    bf16* __restrict__ dstPsf, bf16* __restrict__ dstOffm) {
  __shared__ float tile[64][65];
  const int bid = blockIdx.x;
  const int tid = threadIdx.x;

  if (bid < 258) {
    // ---- zero rings (~1 MB) ----
    const int idx = bid * 256 + tid;  // < 66048 exactly
    const f32x4 z = {0.f, 0.f, 0.f, 0.f};
    int r, chunk;
    char* base;
    if (idx < 33024) {
      chunk = idx & 7;
      int cell = idx >> 3;
      r = cell % 516;
      int bb = cell / 516;
      int b = bb & 3;
      bf16* out = (bb >> 2) ? ctx_t : fs_t;
      int row, col;
      if (r < 130)      { row = 0;   col = r; }
      else if (r < 260) { row = 129; col = r - 130; }
      else { int s = r - 260; row = 1 + (s >> 1); col = (s & 1) ? 129 : 0; }
      base = (char*)(out + ((size_t)(b * HP + row) * HP + col) * 64);
    } else {
      int i2 = idx - 33024;
      chunk = i2 & 15;
      int cell = i2 >> 4;
      r = cell % 516;
      int b = cell / 516;
      int row, col;
      if (r < 130)      { row = 0;   col = r; }
      else if (r < 260) { row = 129; col = r - 130; }
      else { int s = r - 260; row = 1 + (s >> 1); col = (s & 1) ? 129 : 0; }
      base = (char*)(xp + ((size_t)(b * HP + row) * HP + col) * 64);
    }
    *reinterpret_cast<f32x4*>(base + chunk * 16) = z;
    return;
  }

  if (bid < 3330) {
    // ---- transpose_all ----
    const int t = bid - 258;            // 0..3071 = 2 x 128 x 12
    const int bx = t & 1, by = (t >> 1) & 127, bz = t >> 8;
    const int b = bz & 3, which = bz >> 2;
    const float* in = which == 0 ? fs : (which == 1 ? ctx : x);
    const int y = by, x0 = bx * 64;
#pragma unroll
    for (int pass = 0; pass < 16; ++pass) {
      int ci = pass * 4 + (tid >> 6), xx = tid & 63;
      tile[ci][xx] = in[((b * 64 + ci) * HH + y) * WW + x0 + xx];
    }
    __syncthreads();
    if (which == 2) {
#pragma unroll
      for (int pass = 0; pass < 16; ++pass) {
        int xx = pass * 4 + (tid >> 6), ci = tid & 63;
        xp[((size_t)(b * HP + y + 1) * HP + (x0 + xx + 1)) * 64 + ci] = tile[ci][xx];
      }
    } else {
      bf16* out = which ? ctx_t : fs_t;
#pragma unroll
      for (int pass = 0; pass < 16; ++pass) {
        int xx = pass * 4 + (tid >> 6), ci = tid & 63;
        out[((size_t)(b * HP + y + 1) * HP + (x0 + xx + 1)) * 64 + ci] = (bf16)tile[ci][xx];
      }
    }
    return;
  }

  // ---- build_bfrag ----
  const int bx = bid - 3330;            // 0..170
  if (bx < 162) {
    int idx = bx * 256 + tid;           // total 4*18*9*64 = 41472
    int lane = idx & 63;
    int nt = (idx >> 6) % 9;
    int kc = ((idx >> 6) / 9) % 18;
    int cc = (idx >> 6) / 162;
    int np = cc * 144 + nt * 16 + (lane & 15);  // permuted column
    int n = (np & 63) * 9 + (np >> 6);          // original filter channel
    int q = lane >> 4;
    bf16x8 v;
#pragma unroll
    for (int j = 0; j < 8; ++j) {
      int k = kc * 32 + q * 8 + j;
      int tap = k >> 6, ci = k & 63;
      v[j] = (bf16)fw[(n * 64 + ci) * 9 + tap];
    }
    *reinterpret_cast<bf16x8*>(dstPsf + (size_t)idx * 8) = v;
  } else {
    int idx = (bx - 162) * 256 + tid;   // total 18*2*64 = 2304
    int lane = idx & 63;
    int nt = (idx >> 6) & 1;
    int kc = (idx >> 6) >> 1;
    int n = nt * 16 + (lane & 15);
    int q = lane >> 4;
    bf16x8 v;
#pragma unroll
    for (int j = 0; j < 8; ++j) {
      int k = kc * 32 + q * 8 + j;
      int tap = k >> 6, ci = k & 63;
      float w = 0.f;
      if (n < 18) w = pw[(n * 64 + ci) * 9 + tap];
      else if (n < 27) w = mw[((n - 18) * 64 + ci) * 9 + tap];
      v[j] = (bf16)w;
    }
    *reinterpret_cast<bf16x8*>(dstOffm + (size_t)idx * 8) = v;
  }
}

// ---------------------------------------------------------------------------
// Mega kernel v9 = EXACT v6 PSF loop (proven 51.3us, MfmaUtil 36%).
// Ladder evidence brackets this schedule as a local optimum:
//   direct-global B (r4): 86us | (4,2) split (r7): 114us (spills)
//   A-prefetch-pre-barrier (r8): 62us | v6: 51.3us
// 512 thr / 8 waves, (8,1) split, dbuf Bsm, stage(tap+1) issued before
// compute(tap), one barrier per tap.
// ---------------------------------------------------------------------------
__global__ __launch_bounds__(512, 4) void conv_mega(
    const bf16* __restrict__ ctx_t, const bf16* __restrict__ fs_t,
    const bf16* __restrict__ Bf, const bf16* __restrict__ Bf2,
    const float* __restrict__ fb, const float* __restrict__ pb,
    const float* __restrict__ mb, bf16* __restrict__ Pg,
    float* __restrict__ OM, int b0, int offmN) {
  __shared__ __align__(16) char smem[78336];  // apatch 41472 + 2x Bsm 18432
  ushort* apatch = (ushort*)smem;
  const int tid = threadIdx.x;
  const int lane = tid & 63, wv = tid >> 6;   // wv in [0,8)
  const int q = lane >> 4, col = lane & 15;
  const int bid = blockIdx.x;

  if ((int)bid < offmN) {
    // ---------------- offset/mask conv (v6, unchanged) ----------------
    const int b = bid >> 6, t = bid & 63;
    const int h0 = (t >> 3) * 16, w0 = (t & 7) * 16;
    const ushort* Atu = (const ushort*)fs_t;
#pragma unroll
    for (int it = 0; it < 6; ++it) {
      int flat = it * 512 + tid;
      if (flat < 2592) {
        int px = flat >> 3, c8 = flat & 7;
        int py = px / 18, pxx = px - py * 18;
        u16x8 v = *(const u16x8*)(Atu + ((size_t)((b * HP + h0 + py) * HP + (w0 + pxx))) * 64 + c8 * 8);
        *(u16x8*)(apatch + px * 64 + ((c8 ^ (px & 7)) * 8)) = v;
      }
    }
    __syncthreads();
    f32x4 acc[2][2];
#pragma unroll
    for (int s = 0; s < 2; ++s) {
      acc[s][0] = (f32x4){0.f, 0.f, 0.f, 0.f};
      acc[s][1] = (f32x4){0.f, 0.f, 0.f, 0.f};
    }
    const bf16* bl = Bf2 + lane * 8;
#pragma unroll
    for (int dh = 0; dh < 3; ++dh)
#pragma unroll
      for (int dw = 0; dw < 3; ++dw) {
        const int tap = dh * 3 + dw;
        bf16x8 a[2][2];
#pragma unroll
        for (int s = 0; s < 2; ++s) {
          int p = (s * 8 + wv + dh) * 18 + (col + dw);
#pragma unroll
          for (int hf = 0; hf < 2; ++hf) {
            int ch = (hf * 4 + q) ^ (p & 7);
            a[s][hf] = *(const bf16x8*)((const bf16*)apatch + p * 64 + ch * 8);
          }
        }
#pragma unroll
        for (int hf = 0; hf < 2; ++hf)
#pragma unroll
          for (int nt = 0; nt < 2; ++nt) {
            bf16x8 bb = *(const bf16x8*)(bl + (size_t)(((tap * 2 + hf) * 2 + nt) * 512));
#pragma unroll
            for (int s = 0; s < 2; ++s)
              acc[s][nt] = __builtin_amdgcn_mfma_f32_16x16x32_bf16(a[s][hf], bb, acc[s][nt], 0, 0, 0);
          }
      }
    float* OMb = OM + (size_t)b * 16384 * 32;
#pragma unroll
    for (int nt = 0; nt < 2; ++nt) {
      int n = nt * 16 + col;
#pragma unroll
      for (int s = 0; s < 2; ++s) {
        int h = h0 + s * 8 + wv;
#pragma unroll
        for (int j = 0; j < 4; ++j) {
          int w = w0 + q * 4 + j;
          float v = acc[s][nt][j];
          float r;
          if (n < 18) r = v + pb[n];
          else if (n < 27) { float z = v + mb[n - 18]; r = 1.f / (1.f + __expf(-z)); }
          else r = 0.f;
          OMb[(size_t)(h * WW + w) * 32 + n] = r;
        }
      }
    }
    return;
  }

  // ---------------- PSF GEMM (v6: dbuf Bsm, A-reads inside tap) ----------------
  const int pid = bid - offmN;
  const int cc = pid & 3;
  const int rest = pid >> 2;
  const int brel = rest >> 6;
  const int b = b0 + brel;
  const int t = rest & 63;
  const int h0 = (t >> 3) * 16, w0 = (t & 7) * 16;
  char* BsmBase = smem + 41472;
  const char* BfC = (const char*)Bf + (size_t)cc * 165888;  // 18 kc * 9216 B

  // issue tap-0 B stage FIRST (latency hides under apatch staging)
  {
    const char* gs = BfC;
#pragma unroll
    for (int it = 0; it < 3; ++it) {
      int flat = it * 512 + wv * 64;
      if (flat < 1152) {
        __builtin_amdgcn_global_load_lds(
            (const __attribute__((address_space(1))) void*)(gs + (size_t)(flat + lane) * 16),
            (__attribute__((address_space(3))) void*)(BsmBase + flat * 16), 16, 0, 0);
      }
    }
  }

  const ushort* Atu = (const ushort*)ctx_t;
#pragma unroll
  for (int it = 0; it < 6; ++it) {
    int flat = it * 512 + tid;
    if (flat < 2592) {
      int px = flat >> 3, c8 = flat & 7;
      int py = px / 18, pxx = px - py * 18;
      u16x8 v = *(const u16x8*)(Atu + ((size_t)((b * HP + h0 + py) * HP + (w0 + pxx))) * 64 + c8 * 8);
      *(u16x8*)(apatch + px * 64 + ((c8 ^ (px & 7)) * 8)) = v;
    }
  }
  __syncthreads();   // apatch + tap-0 Bsm ready (vmcnt drained)

  f32x4 acc[2][9];
#pragma unroll
  for (int s = 0; s < 2; ++s)
#pragma unroll
    for (int n = 0; n < 9; ++n) acc[s][n] = (f32x4){0.f, 0.f, 0.f, 0.f};

  for (int tap = 0; tap < 9; ++tap) {
    const int cur = tap & 1;
    // issue NEXT tap's stage before this tap's compute (latency overlap)
    if (tap < 8) {
      const char* gs = BfC + (tap + 1) * 18432;
      char* ld = BsmBase + (cur ^ 1) * 18432;
#pragma unroll
      for (int it = 0; it < 3; ++it) {
        int flat = it * 512 + wv * 64;     // wave-uniform chunk base
        if (flat < 1152) {
          __builtin_amdgcn_global_load_lds(
              (const __attribute__((address_space(1))) void*)(gs + (size_t)(flat + lane) * 16),
              (__attribute__((address_space(3))) void*)(ld + flat * 16), 16, 0, 0);
        }
      }
    }

    const int dh = tap >= 6 ? 2 : (tap >= 3 ? 1 : 0);
    const int dw = tap - dh * 3;
    bf16x8 a[2][2];
#pragma unroll
    for (int s = 0; s < 2; ++s) {
      int p = (s * 8 + wv + dh) * 18 + (col + dw);
#pragma unroll
      for (int hf = 0; hf < 2; ++hf) {
        int ch = (hf * 4 + q) ^ (p & 7);
        a[s][hf] = *(const bf16x8*)((const bf16*)apatch + p * 64 + ch * 8);
      }
    }
    const bf16* Bsm = (const bf16*)(BsmBase + cur * 18432);
#pragma unroll
    for (int hf = 0; hf < 2; ++hf) {
      const bf16* bp = Bsm + (size_t)(hf * 9) * 512 + lane * 8;
#pragma unroll
      for (int nt = 0; nt < 9; ++nt) {
        bf16x8 bb = *(const bf16x8*)(bp + nt * 512);
#pragma unroll
        for (int s = 0; s < 2; ++s)
          acc[s][nt] = __builtin_amdgcn_mfma_f32_16x16x32_bf16(a[s][hf], bb, acc[s][nt], 0, 0, 0);
      }
    }
    // one barrier per tap: buf[cur] reads done; implicit vmcnt drain
    // completes the tap+1 stage (mostly already landed under the MFMAs)
    __syncthreads();
  }

  // epilogue: P[px][n'] (n' = t9*64 + c), bias via inverse permutation
  bf16* Pp = Pg + (size_t)brel * 16384 * 576;
#pragma unroll
  for (int nt = 0; nt < 9; ++nt) {
    int np = cc * 144 + nt * 16 + col;
    float bias = fb[(np & 63) * 9 + (np >> 6)];
#pragma unroll
    for (int s = 0; s < 2; ++s) {
      int h = h0 + s * 8 + wv;
#pragma unroll
      for (int j = 0; j < 4; ++j) {
        int w = w0 + q * 4 + j;
        Pp[(size_t)(h * WW + w) * 576 + np] = (bf16)(acc[s][nt][j] + bias);
      }
    }
  }
}

// ---------------------------------------------------------------------------
// Sampler v3: two-phase (per-(pixel,tap) weights computed ONCE in LDS, not
// 64x per channel) at proven occupancy (256,4). Boundary taps skipped.
// ---------------------------------------------------------------------------
__global__ __launch_bounds__(256, 4) void sampler(
    const bf16* __restrict__ Pg, const float* __restrict__ xp,
    const float* __restrict__ OM, float* __restrict__ out, int b0) {
  __shared__ float smem[64][21];
  __shared__ __align__(16) float wts[144][4];
  __shared__ __align__(16) int   offs[144][4];
  const int tid = threadIdx.x;
  const int wv = tid >> 6, c = tid & 63;
  const int blk = blockIdx.x;
  const int brel = blk >> 10;
  const int b = b0 + brel;
  const int h = (blk >> 3) & 127;
  const int w0 = (blk & 7) * 16;

  const float* xpb = xp + (size_t)b * (HP * HP * 64) + c;
  const float* OMb = OM + (size_t)b * 16384 * 32;
  const bf16* Pbase = Pg + ((size_t)brel * 16384 + h * WW + w0) * 576;

  // ---- phase 1: per-(pixel,tap) weights, computed once (not per channel) ----
  if (tid < 144) {
    const int pl = tid / 9, tap = tid - pl * 9;   // tap = i3*3+j3
    const int i3 = tap / 3, j3 = tap - i3 * 3;
    const int dh = (i3 == 0) ? -1 : 0, ri = (i3 == 0) ? 2 : (i3 - 1);
    const int dw = (j3 == 0) ? -1 : 0, rj = (j3 == 0) ? 2 : (j3 - 1);
    const int hh = h + dh, ww2 = w0 + pl + dw;
    f32x4 g = {0.f, 0.f, 0.f, 0.f};
    i32x4 o = {0, 0, 0, 0};
    if (hh >= 0 && ww2 >= 0) {
      const int np = ri * 3 + rj;
      const float* omp = OMb + (size_t)(hh * WW + ww2) * 32;
      float ox = omp[np], oy = omp[9 + np], mv = omp[18 + np];
      float px = (float)(hh + ri) + ox;
      float py = (float)(ww2 + rj) + oy;
      float fx = floorf(px), fy = floorf(py);
      float ltx = fminf(fmaxf(fx, 0.f), 129.f);
      float lty = fminf(fmaxf(fy, 0.f), 129.f);
      float rbx = fminf(fmaxf(fx + 1.f, 0.f), 129.f);
      float rby = fminf(fmaxf(fy + 1.f, 0.f), 129.f);
      float pxc = fminf(fmaxf(px, 0.f), 129.f);
      float pyc = fminf(fmaxf(py, 0.f), 129.f);
      g[0] = (1.f + ltx - pxc) * (1.f + lty - pyc) * mv;  // lt
      g[1] = (1.f - rbx + pxc) * (1.f - rby + pyc) * mv;  // rb
      g[2] = (1.f + ltx - pxc) * (1.f - rby + pyc) * mv;  // lb
      g[3] = (1.f - rbx + pxc) * (1.f + lty - pyc) * mv;  // rt
      int ix0 = (int)ltx, iy0 = (int)lty, ix1 = (int)rbx, iy1 = (int)rby;
      o[0] = (ix0 * HP + iy0) * 64;
      o[1] = (ix1 * HP + iy1) * 64;
      o[2] = (ix0 * HP + iy1) * 64;
      o[3] = (ix1 * HP + iy0) * 64;
    }
    *reinterpret_cast<f32x4*>(&wts[tid][0]) = g;
    *reinterpret_cast<i32x4*>(&offs[tid][0]) = o;
  }
  __syncthreads();

  // ---- phase 2: channel-parallel gather + FMA ----
#pragma unroll
  for (int k = 0; k < 4; ++k) {
    const int pl = wv * 4 + k;
    const int w = w0 + pl;
    const bf16* Pp = Pbase + (size_t)pl * 576;
    float res = 0.f;
#pragma unroll
    for (int tap = 0; tap < 9; ++tap) {
      const int i3 = tap / 3, j3 = tap - i3 * 3;
      if ((i3 == 0 && h == 0) || (j3 == 0 && w == 0)) continue;  // wave-uniform skip
      const int idx = pl * 9 + tap;
      f32x4 g = *reinterpret_cast<const f32x4*>(&wts[idx][0]);   // uniform bcast
      i32x4 o = *reinterpret_cast<const i32x4*>(&offs[idx][0]);  // uniform bcast
      float x_lt = xpb[o[0]];
      float x_rb = xpb[o[1]];
      float x_lb = xpb[o[2]];
      float x_rt = xpb[o[3]];
      float sv = g[0] * x_lt + g[1] * x_rb + g[2] * x_lb + g[3] * x_rt;
      float pv = (float)Pp[tap * 64 + c];
      res += pv * sv;
    }
    smem[c][pl] = res;
  }
  __syncthreads();
  const int c2 = tid >> 2;
  const int wi = (tid & 3) * 4;
  f32x4 v;
#pragma unroll
  for (int i = 0; i < 4; ++i) v[i] = smem[c2][wi + i];
  *reinterpret_cast<f32x4*>(out + ((size_t)(b * 64 + c2) * HH + h) * WW + w0 + wi) = v;
}

// ---------------------------------------------------------------------------
extern "C" void kernel_launch(void* const* d_in, const int* in_sizes, int n_in,
                              void* d_out, int out_size, void* d_ws, size_t ws_size,
                              hipStream_t stream) {
  (void)in_sizes; (void)n_in; (void)out_size;
  const float* fs  = (const float*)d_in[0];
  const float* ctx = (const float*)d_in[1];
  const float* x   = (const float*)d_in[2];
  const float* pw  = (const float*)d_in[3];
  const float* pb  = (const float*)d_in[4];
  const float* fw  = (const float*)d_in[5];
  const float* fb  = (const float*)d_in[6];
  const float* mw  = (const float*)d_in[7];
  const float* mb  = (const float*)d_in[8];

  char* ws = (char*)d_ws;
  bf16*  ctx_t = (bf16*)(ws);                   //  8,652,800
  bf16*  fs_t  = (bf16*)(ws + 8652800);         //  8,652,800
  float* xp    = (float*)(ws + 17305600);       // 17,305,600
  bf16*  Bf    = (bf16*)(ws + 34611200);        //    663,552
  bf16*  Bf2   = (bf16*)(ws + 35274752);        //     36,864
  float* OM    = (float*)(ws + 35311616);       //  8,388,608
  bf16*  Pg    = (bf16*)(ws + 43700224);        // 18,874,368 per batch

  // one prep launch: ring-zero + transposes + B-frag builds
  prep<<<3501, 256, 0, stream>>>(fs, ctx, x, fw, pw, mw,
                                 fs_t, ctx_t, xp, Bf, Bf2);

  const size_t need4 = 43700224 + 4ull * 18874368;  // 119,197,696 B for 4-batch Pg
  if (ws_size >= need4) {
    // merged path (live: WRITE_SIZE evidence shows 4-batch Pg fits)
    conv_mega<<<1280, 512, 0, stream>>>(ctx_t, fs_t, Bf, Bf2, fb, pb, mb, Pg, OM, 0, 256);
    sampler<<<4096, 256, 0, stream>>>(Pg, xp, OM, (float*)d_out, 0);
  } else {
    // fallback 2-batch split (Pg holds 2 batches)
    conv_mega<<<768, 512, 0, stream>>>(ctx_t, fs_t, Bf, Bf2, fb, pb, mb, Pg, OM, 0, 256);
    sampler<<<2048, 256, 0, stream>>>(Pg, xp, OM, (float*)d_out, 0);
    conv_mega<<<512, 512, 0, stream>>>(ctx_t, fs_t, Bf, Bf2, fb, pb, mb, Pg, OM, 2, 0);
    sampler<<<2048, 256, 0, stream>>>(Pg, xp, OM, (float*)d_out, 2);
  }
}